// Round 9
// baseline (433.365 us; speedup 1.0000x reference)
//
#include <hip/hip_runtime.h>
#include <hip/hip_bf16.h>

#define HID 128
#define NCLASS 10
#define PCHUNK 8192
#define HB 256  // hist partner blocks

typedef unsigned int uint;
typedef unsigned short ushort;
typedef __attribute__((ext_vector_type(8))) __bf16 bf16x8;
typedef __attribute__((ext_vector_type(4))) float f32x4;

// ---- bf16 helpers -----------------------------------------------------------
__device__ __forceinline__ uint bf16rne(float x) {
    uint u = __float_as_uint(x);
    return (u + 0x7FFFu + ((u >> 16) & 1u)) >> 16;
}
__device__ __forceinline__ uint pack2(float e0, float e1) {
    return bf16rne(e0) | (bf16rne(e1) << 16);
}
__device__ __forceinline__ void unpack2(uint w, float& lo, float& hi) {
    lo = __uint_as_float(w << 16);
    hi = __uint_as_float(w & 0xFFFF0000u);
}
__device__ __forceinline__ void split2(float e0, float e1, uint& h, uint& l) {
    uint h0 = bf16rne(e0), h1 = bf16rne(e1);
    float r0 = e0 - __uint_as_float(h0 << 16);
    float r1 = e1 - __uint_as_float(h1 << 16);
    h = h0 | (h1 << 16);
    l = bf16rne(r0) | (bf16rne(r1) << 16);
}
__device__ __forceinline__ bf16x8 as_bf16x8(uint4 u) {
    return __builtin_bit_cast(bf16x8, u);
}
__device__ __forceinline__ void unpack8(uint4 u, float* f) {
    unpack2(u.x, f[0], f[1]); unpack2(u.y, f[2], f[3]);
    unpack2(u.z, f[4], f[5]); unpack2(u.w, f[6], f[7]);
}

// ---- W pre-pack device body (fragment order, hi/lo planes) ------------------
__device__ __forceinline__ void pack_w_body(const float* __restrict__ W,
                                            uint* __restrict__ hi, uint* __restrict__ lo,
                                            int slot, int l) {
    const int s = slot >> 3, t = slot & 7;
    const int kb = s * 32 + (l >> 4) * 8, n = t * 16 + (l & 15);
    float f[8];
#pragma unroll
    for (int j = 0; j < 8; ++j) f[j] = W[(kb + j) * HID + n];
    uint4 h, lo4;
    split2(f[0], f[1], h.x, lo4.x);
    split2(f[2], f[3], h.y, lo4.y);
    split2(f[4], f[5], h.z, lo4.z);
    split2(f[6], f[7], h.w, lo4.w);
    const int fo = (slot * 64 + l) * 4;
    *(uint4*)(hi + fo) = h;
    *(uint4*)(lo + fo) = lo4;
}

// fat: bucket histogram (blocks 0..HB-1) || pack W1 (HB..HB+7) || pack W2 (HB+8..HB+15)
__global__ __launch_bounds__(256) void hist_pack_kernel(
        const int* __restrict__ dst, int* __restrict__ bcnt, int E, int NB,
        const float* __restrict__ W1, uint* __restrict__ W1hi, uint* __restrict__ W1lo,
        const float* __restrict__ W2, uint* __restrict__ W2hi, uint* __restrict__ W2lo) {
    __shared__ int h[400];
    const int t = threadIdx.x;
    if ((int)blockIdx.x < HB) {
        const int ech = (E + HB - 1) / HB;
        const int e0 = blockIdx.x * ech;
        const int e1 = min(E, e0 + ech);
        for (int i = t; i < NB; i += 256) h[i] = 0;
        __syncthreads();
        for (int e = e0 + t; e < e1; e += 256) atomicAdd(&h[dst[e] >> 8], 1);
        __syncthreads();
        for (int i = t; i < NB; i += 256)
            if (h[i]) atomicAdd(&bcnt[i], h[i]);
    } else {
        const int pb = blockIdx.x - HB;
        const int slot = (pb & 7) * 4 + (t >> 6);
        const int l = t & 63;
        if (pb < 8) pack_w_body(W1, W1hi, W1lo, slot, l);
        else        pack_w_body(W2, W2hi, W2lo, slot, l);
    }
}

// ================================================================ MFMA GEMM (A=W, B=X)
// Output HS is SLICED: HS[slice][node][16 features], 16 bf16 = 8 uints per (slice,node).
// FP32IN: X fp32 (full row-major), 3-term split. else: X = bf16 hi plane, SLICED layout, 2-term.
template <bool FP32IN>
__device__ __forceinline__ void gemm_body_mfma(
        const float* __restrict__ Xf, const uint* __restrict__ Xhi,
        const uint* __restrict__ Wphi, const uint* __restrict__ Wplo,
        uint* __restrict__ HS, int N, int bidx, int tid) {
    const int wv = tid >> 6;
    const int l = tid & 63;
    const int q = l >> 4;
    const int cm = l & 15;
    const long rowbase = (long)bidx * 128 + wv * 32;

    bf16x8 bhi[2][4], blo[2][4];
#pragma unroll
    for (int rt = 0; rt < 2; ++rt) {
        const long row = rowbase + rt * 16 + cm;
        const long rc = row < N ? row : (N - 1);
#pragma unroll
        for (int s = 0; s < 4; ++s) {
            if (FP32IN) {
                const float* xp = Xf + rc * HID + s * 32 + q * 8;
                const float4 a0 = ((const float4*)xp)[0];
                const float4 a1 = ((const float4*)xp)[1];
                uint4 h, lo4;
                split2(a0.x, a0.y, h.x, lo4.x);
                split2(a0.z, a0.w, h.y, lo4.y);
                split2(a1.x, a1.y, h.z, lo4.z);
                split2(a1.z, a1.w, h.w, lo4.w);
                bhi[rt][s] = as_bf16x8(h);
                blo[rt][s] = as_bf16x8(lo4);
            } else {
                // features f = s*32 + q*8 -> slice = 2s + (q>>1), half = q&1
                const size_t o = ((size_t)(2 * s + (q >> 1)) * N + rc) * 2 + (q & 1);  // uint4 units
                bhi[rt][s] = as_bf16x8(((const uint4*)Xhi)[o]);
            }
        }
    }

    f32x4 acc[2][8];
#pragma unroll
    for (int rt = 0; rt < 2; ++rt)
#pragma unroll
        for (int t = 0; t < 8; ++t) acc[rt][t] = (f32x4)0.0f;

#pragma unroll
    for (int s = 0; s < 4; ++s) {
#pragma unroll
        for (int t = 0; t < 8; ++t) {
            const int fo = ((s * 8 + t) * 64 + l) * 4;
            const bf16x8 whi = as_bf16x8(*(const uint4*)(Wphi + fo));
            const bf16x8 wlo = as_bf16x8(*(const uint4*)(Wplo + fo));
#pragma unroll
            for (int rt = 0; rt < 2; ++rt) {
                acc[rt][t] = __builtin_amdgcn_mfma_f32_16x16x32_bf16(whi, bhi[rt][s], acc[rt][t], 0, 0, 0);
                if (FP32IN)
                    acc[rt][t] = __builtin_amdgcn_mfma_f32_16x16x32_bf16(whi, blo[rt][s], acc[rt][t], 0, 0, 0);
                acc[rt][t] = __builtin_amdgcn_mfma_f32_16x16x32_bf16(wlo, bhi[rt][s], acc[rt][t], 0, 0, 0);
            }
        }
    }

    // epilogue: features f = t*16 + q*4 -> slice = t, uint offset q*2 within the 8-uint chunk
#pragma unroll
    for (int rt = 0; rt < 2; ++rt) {
        const long row = rowbase + rt * 16 + cm;
        if (row < N) {
#pragma unroll
            for (int t = 0; t < 8; ++t) {
                uint2 o;
                o.x = pack2(acc[rt][t][0], acc[rt][t][1]);
                o.y = pack2(acc[rt][t][2], acc[rt][t][3]);
                *(uint2*)&HS[((size_t)t * N + row) * 8 + q * 2] = o;
            }
        }
    }
}

// fat: partition (blocks 0..PB-1, starts immediately) || gemm1 (PB..PB+GB-1)
__global__ __launch_bounds__(256) void gemm1_part_kernel(
        const float* __restrict__ emb, const uint* __restrict__ Wphi,
        const uint* __restrict__ Wplo, uint* __restrict__ HS, int N,
        const int* __restrict__ src, const int* __restrict__ dst,
        int* __restrict__ gcursor, uint* __restrict__ staged, int E, int PB, int NB) {
    __shared__ int hist[400], lbase[400], loff[400];
    const int t = threadIdx.x;
    if ((int)blockIdx.x >= PB) {
        gemm_body_mfma<true>(emb, nullptr, Wphi, Wplo, HS, N, blockIdx.x - PB, t);
        return;
    }
    const int e0 = blockIdx.x * PCHUNK;
    for (int i = t; i < NB; i += 256) { hist[i] = 0; loff[i] = 0; }
    __syncthreads();
#pragma unroll
    for (int j = 0; j < PCHUNK / 256; ++j) {
        const int e = e0 + j * 256 + t;
        if (e < E) atomicAdd(&hist[dst[e] >> 8], 1);
    }
    __syncthreads();
    for (int b = t; b < NB; b += 256)
        if (hist[b] > 0) lbase[b] = atomicAdd(&gcursor[b], hist[b]);
    __syncthreads();
#pragma unroll
    for (int j = 0; j < PCHUNK / 256; ++j) {
        const int e = e0 + j * 256 + t;
        if (e < E) {
            const int d = dst[e];
            const int b = d >> 8;
            const int pos = lbase[b] + atomicAdd(&loff[b], 1);
            staged[pos] = (uint)src[e] | ((uint)(d & 255) << 17);
        }
    }
}

__global__ __launch_bounds__(256) void gemm2_kernel(
        const uint* __restrict__ Xhi, const uint* __restrict__ Wphi,
        const uint* __restrict__ Wplo, uint* __restrict__ HS, int N) {
    gemm_body_mfma<false>(nullptr, Xhi, Wphi, Wplo, HS, N, blockIdx.x, threadIdx.x);
}

// ================================================================ bucket scan (writes rps[N]=E sentinel)
__global__ __launch_bounds__(512) void scan_buckets_kernel(const int* __restrict__ bcnt,
                                                           int* bbase, int* gcursor,
                                                           int* rps, int NB, int E, int N) {
    __shared__ int sh[512];
    const int t = threadIdx.x;
    const int v = (t < NB) ? bcnt[t] : 0;
    sh[t] = v;
    __syncthreads();
    for (int off = 1; off < 512; off <<= 1) {
        int x = (t >= off) ? sh[t - off] : 0;
        __syncthreads();
        sh[t] += x;
        __syncthreads();
    }
    const int excl = sh[t] - v;
    if (t < NB) { bbase[t] = excl; gcursor[t] = excl; }
    if (t == NB - 1) bbase[NB] = excl + v;
    if (t == 0) rps[N] = E;
}

// ================================================================ fill: per-bucket deg/scan/invs/col
__global__ __launch_bounds__(256) void fill_bucket_kernel(
        const uint* __restrict__ staged, const int* __restrict__ bbase,
        int* __restrict__ rps, float* __restrict__ invs, int* __restrict__ col, int N) {
    __shared__ int h[256], cur[256], sh[256];
    const int b = blockIdx.x, t = threadIdx.x;
    const int w0 = bbase[b], w1 = bbase[b + 1];
    const int base0 = b << 8;
    h[t] = 0;
    __syncthreads();
    for (int i = w0 + t; i < w1; i += 256) atomicAdd(&h[staged[i] >> 17], 1);
    __syncthreads();
    const int my = h[t];
    sh[t] = my;
    __syncthreads();
    for (int off = 1; off < 256; off <<= 1) {
        int x = (t >= off) ? sh[t - off] : 0;
        __syncthreads();
        sh[t] += x;
        __syncthreads();
    }
    const int start = w0 + sh[t] - my;
    cur[t] = start;
    const int node = base0 + t;
    if (node < N) {
        rps[node] = start;
        invs[node] = rsqrtf((float)my + 1.0f);
    }
    __syncthreads();
    for (int i = w0 + t; i < w1; i += 256) {
        const uint u = staged[i];
        const int p = atomicAdd(&cur[u >> 17], 1);
        col[p] = (int)(u & 0x1FFFFu);
    }
}

// ================================================================ XCD-sharded pull
// slice = blockIdx.x & 7 (round-robin XCD locality: slice table 3.2MB < 4MB L2).
// 2 lanes/node (16 features/slice), batch-8 edge gathers of uint4.
// LAYER1: out = invs*relu(acc*invs + b) (pre-scaled X1'); else out = relu(acc*invs + b).
template <bool LAYER1>
__global__ __launch_bounds__(256) void pull_sliced_kernel(
        const int* __restrict__ rps, const int* __restrict__ col,
        const uint* __restrict__ Hs, const float* __restrict__ invs,
        const float* __restrict__ bias, uint* __restrict__ Xout, int N) {
    const int slice = blockIdx.x & 7;
    const int chunk = blockIdx.x >> 3;
    const int t = threadIdx.x;
    const int node = chunk * 128 + (t >> 1);
    if (node >= N) return;
    const int half = t & 1;
    const uint4* H4 = (const uint4*)Hs;
    const size_t sbase = (size_t)slice * N;

    const int p = rps[node];
    const int d = rps[node + 1] - p;
    const float sn = invs[node];

    float acc[8];
    {
        float f[8];
        unpack8(H4[(sbase + node) * 2 + half], f);
#pragma unroll
        for (int j = 0; j < 8; ++j) acc[j] = LAYER1 ? f[j] * sn : f[j];  // self-loop
    }
    int i = 0;
    for (; i + 8 <= d; i += 8) {
        int s[8];
#pragma unroll
        for (int k = 0; k < 8; ++k) s[k] = col[p + i + k];
        uint4 a[8];
#pragma unroll
        for (int k = 0; k < 8; ++k) a[k] = H4[(sbase + s[k]) * 2 + half];
        float w[8];
        if (LAYER1) {
#pragma unroll
            for (int k = 0; k < 8; ++k) w[k] = invs[s[k]];
        }
#pragma unroll
        for (int k = 0; k < 8; ++k) {
            float f[8];
            unpack8(a[k], f);
#pragma unroll
            for (int j = 0; j < 8; ++j) acc[j] += LAYER1 ? f[j] * w[k] : f[j];
        }
    }
    for (; i + 2 <= d; i += 2) {
        const int s0 = col[p + i], s1 = col[p + i + 1];
        const uint4 a0 = H4[(sbase + s0) * 2 + half];
        const uint4 a1 = H4[(sbase + s1) * 2 + half];
        float w0 = 1.0f, w1 = 1.0f;
        if (LAYER1) { w0 = invs[s0]; w1 = invs[s1]; }
        float f0[8], f1[8];
        unpack8(a0, f0); unpack8(a1, f1);
#pragma unroll
        for (int j = 0; j < 8; ++j) acc[j] += LAYER1 ? (f0[j] * w0 + f1[j] * w1) : (f0[j] + f1[j]);
    }
    if (i < d) {
        const int s0 = col[p + i];
        const float w0 = LAYER1 ? invs[s0] : 1.0f;
        float f[8];
        unpack8(H4[(sbase + s0) * 2 + half], f);
#pragma unroll
        for (int j = 0; j < 8; ++j) acc[j] += LAYER1 ? f[j] * w0 : f[j];
    }
    float x[8];
#pragma unroll
    for (int j = 0; j < 8; ++j) {
        const float r = fmaxf(acc[j] * sn + bias[slice * 16 + half * 8 + j], 0.0f);
        x[j] = LAYER1 ? sn * r : r;
    }
    uint4 h;
    h.x = pack2(x[0], x[1]); h.y = pack2(x[2], x[3]);
    h.z = pack2(x[4], x[5]); h.w = pack2(x[6], x[7]);
    ((uint4*)Xout)[(sbase + node) * 2 + half] = h;
}

// ================================================================ final out-GEMM (128->10) from sliced x2
// 16 lanes/node; lane covers features lane*8..lane*8+7 = slice (lane>>1), half (lane&1).
__global__ __launch_bounds__(256) void out_gemm_kernel(
        const uint* __restrict__ X2s, const float* __restrict__ Wout,
        const float* __restrict__ bout, float* __restrict__ OUT, int N) {
    __shared__ float Wd[320 * 4];
    for (int t = threadIdx.x; t < 320; t += 256) {
        const int c = t >> 5, rem = t & 31, j4 = rem >> 4, l = rem & 15;
        const int k0 = l * 8 + j4 * 4;
        float4 w;
        w.x = Wout[(k0 + 0) * NCLASS + c];
        w.y = Wout[(k0 + 1) * NCLASS + c];
        w.z = Wout[(k0 + 2) * NCLASS + c];
        w.w = Wout[(k0 + 3) * NCLASS + c];
        ((float4*)Wd)[(c * 2 + j4) * 16 + l] = w;
    }
    __syncthreads();

    const int g = blockIdx.x * 256 + threadIdx.x;
    const int node = g >> 4;
    if (node >= N) return;
    const int lane = g & 15;
    const uint4 u = ((const uint4*)X2s)[((size_t)(lane >> 1) * N + node) * 2 + (lane & 1)];
    float x[8];
    unpack8(u, x);

    const float4 xv0 = make_float4(x[0], x[1], x[2], x[3]);
    const float4 xv1 = make_float4(x[4], x[5], x[6], x[7]);
    const float4* Wd4 = (const float4*)Wd;
    float res = 0.0f;
#pragma unroll
    for (int c = 0; c < NCLASS; ++c) {
        const float4 w0 = Wd4[(c * 2 + 0) * 16 + lane];
        const float4 w1 = Wd4[(c * 2 + 1) * 16 + lane];
        float s = xv0.x * w0.x + xv0.y * w0.y + xv0.z * w0.z + xv0.w * w0.w
                + xv1.x * w1.x + xv1.y * w1.y + xv1.z * w1.z + xv1.w * w1.w;
        s += __shfl_xor(s, 1, 16);
        s += __shfl_xor(s, 2, 16);
        s += __shfl_xor(s, 4, 16);
        s += __shfl_xor(s, 8, 16);
        if (lane == c) res = s;
    }
    if (lane < NCLASS) OUT[(size_t)node * NCLASS + lane] = res + bout[lane];
}

// ================================================================ launch
extern "C" void kernel_launch(void* const* d_in, const int* in_sizes, int n_in,
                              void* d_out, int out_size, void* d_ws, size_t ws_size,
                              hipStream_t stream) {
    const int* ei     = (const int*)d_in[0];
    const float* emb  = (const float*)d_in[1];
    const float* W1   = (const float*)d_in[2];
    const float* b1   = (const float*)d_in[3];
    const float* W2   = (const float*)d_in[4];
    const float* b2   = (const float*)d_in[5];
    const float* Wout = (const float*)d_in[6];
    const float* bout = (const float*)d_in[7];
    float* out        = (float*)d_out;

    const int E = in_sizes[0] / 2;
    const int N = in_sizes[1] / HID;
    const int* src = ei;
    const int* dst = ei + E;
    (void)ws_size; (void)n_in; (void)out_size;

    const int GB = (N + 127) / 128;            // 782 gemm blocks
    const int NB = (N + 255) >> 8;             // 391 buckets
    const int PB = (E + PCHUNK - 1) / PCHUNK;  // 196 partition blocks
    const int NC = (N + 127) / 128;            // pull node-chunks per slice

    char* ws = (char*)d_ws;
    size_t off = 0;
    auto alloc = [&](size_t bytes) {
        void* p = ws + off;
        off = (off + bytes + 4095) & ~(size_t)4095;
        return p;
    };
    int*   bcnt    = (int*)alloc(512 * 4);
    int*   bbase   = (int*)alloc(512 * 4);
    int*   gcursor = (int*)alloc(512 * 4);
    int*   rps     = (int*)alloc((size_t)(N + 1) * 4);
    float* invs    = (float*)alloc((size_t)N * 4);
    int*   col     = (int*)alloc((size_t)E * 4);
    uint*  staged  = (uint*)alloc((size_t)E * 4);
    uint*  Wp1hi   = (uint*)alloc(HID * HID * 2);
    uint*  Wp1lo   = (uint*)alloc(HID * HID * 2);
    uint*  Wp2hi   = (uint*)alloc(HID * HID * 2);
    uint*  Wp2lo   = (uint*)alloc(HID * HID * 2);
    uint*  HS      = (uint*)alloc((size_t)N * HID * 2);  // sliced bf16 features (both layers)
    uint*  X1hi    = (uint*)alloc((size_t)N * HID * 2);  // sliced bf16 hidden
    uint*  X2s     = (uint*)alloc((size_t)N * HID * 2);  // sliced bf16 relu'd layer-2

    hipMemsetAsync(bcnt, 0, 512 * 4, stream);
    // bucket histogram || pack W1/W2
    hist_pack_kernel<<<HB + 16, 256, 0, stream>>>(dst, bcnt, E, NB,
                                                  W1, Wp1hi, Wp1lo, W2, Wp2hi, Wp2lo);
    scan_buckets_kernel<<<1, 512, 0, stream>>>(bcnt, bbase, gcursor, rps, NB, E, N);
    // partition (blocks 0..PB-1) || gemm1 emb@W1 -> HS1 (sliced bf16)
    gemm1_part_kernel<<<PB + GB, 256, 0, stream>>>(emb, Wp1hi, Wp1lo, HS, N,
                                                   src, dst, gcursor, staged, E, PB, NB);
    fill_bucket_kernel<<<NB, 256, 0, stream>>>(staged, bbase, rps, invs, col, N);

    // layer 1 aggregate -> X1' = invs*relu(...) (sliced, XCD-sharded)
    pull_sliced_kernel<true><<<NC * 8, 256, 0, stream>>>(rps, col, HS, invs, b1, X1hi, N);

    // layer 2: H2' = X1'@W2 (sliced in/out), aggregate -> x2 = relu(...) (sliced)
    gemm2_kernel<<<GB, 256, 0, stream>>>(X1hi, Wp2hi, Wp2lo, HS, N);
    pull_sliced_kernel<false><<<NC * 8, 256, 0, stream>>>(rps, col, HS, invs, b2, X2s, N);

    // final: out = x2 @ Wout + bout
    out_gemm_kernel<<<((size_t)N * 16 + 255) / 256, 256, 0, stream>>>(X2s, Wout, bout, out, N);
}

// Round 10
// 317.564 us; speedup vs baseline: 1.3647x; 1.3647x over previous
//
#include <hip/hip_runtime.h>
#include <hip/hip_bf16.h>

#define HID 128
#define NCLASS 10
#define PCHUNK 8192
#define HB 256  // hist partner blocks

typedef unsigned int uint;
typedef unsigned short ushort;
typedef __attribute__((ext_vector_type(8))) __bf16 bf16x8;
typedef __attribute__((ext_vector_type(4))) float f32x4;

// ---- bf16 helpers -----------------------------------------------------------
__device__ __forceinline__ uint bf16rne(float x) {
    uint u = __float_as_uint(x);
    return (u + 0x7FFFu + ((u >> 16) & 1u)) >> 16;
}
__device__ __forceinline__ uint pack2(float e0, float e1) {
    return bf16rne(e0) | (bf16rne(e1) << 16);
}
__device__ __forceinline__ void unpack2(uint w, float& lo, float& hi) {
    lo = __uint_as_float(w << 16);
    hi = __uint_as_float(w & 0xFFFF0000u);
}
__device__ __forceinline__ void split2(float e0, float e1, uint& h, uint& l) {
    uint h0 = bf16rne(e0), h1 = bf16rne(e1);
    float r0 = e0 - __uint_as_float(h0 << 16);
    float r1 = e1 - __uint_as_float(h1 << 16);
    h = h0 | (h1 << 16);
    l = bf16rne(r0) | (bf16rne(r1) << 16);
}
__device__ __forceinline__ bf16x8 as_bf16x8(uint4 u) {
    return __builtin_bit_cast(bf16x8, u);
}
__device__ __forceinline__ void unpack8(uint4 u, float* f) {
    unpack2(u.x, f[0], f[1]); unpack2(u.y, f[2], f[3]);
    unpack2(u.z, f[4], f[5]); unpack2(u.w, f[6], f[7]);
}

// ---- W pre-pack device body (fragment order, hi/lo planes) ------------------
__device__ __forceinline__ void pack_w_body(const float* __restrict__ W,
                                            uint* __restrict__ hi, uint* __restrict__ lo,
                                            int slot, int l) {
    const int s = slot >> 3, t = slot & 7;
    const int kb = s * 32 + (l >> 4) * 8, n = t * 16 + (l & 15);
    float f[8];
#pragma unroll
    for (int j = 0; j < 8; ++j) f[j] = W[(kb + j) * HID + n];
    uint4 h, lo4;
    split2(f[0], f[1], h.x, lo4.x);
    split2(f[2], f[3], h.y, lo4.y);
    split2(f[4], f[5], h.z, lo4.z);
    split2(f[6], f[7], h.w, lo4.w);
    const int fo = (slot * 64 + l) * 4;
    *(uint4*)(hi + fo) = h;
    *(uint4*)(lo + fo) = lo4;
}

// fat: bucket histogram (blocks 0..HB-1) || pack W1 (HB..HB+7) || pack W2 (HB+8..HB+15)
__global__ __launch_bounds__(256) void hist_pack_kernel(
        const int* __restrict__ dst, int* __restrict__ bcnt, int E, int NB,
        const float* __restrict__ W1, uint* __restrict__ W1hi, uint* __restrict__ W1lo,
        const float* __restrict__ W2, uint* __restrict__ W2hi, uint* __restrict__ W2lo) {
    __shared__ int h[400];
    const int t = threadIdx.x;
    if ((int)blockIdx.x < HB) {
        const int ech = (E + HB - 1) / HB;
        const int e0 = blockIdx.x * ech;
        const int e1 = min(E, e0 + ech);
        for (int i = t; i < NB; i += 256) h[i] = 0;
        __syncthreads();
        for (int e = e0 + t; e < e1; e += 256) atomicAdd(&h[dst[e] >> 8], 1);
        __syncthreads();
        for (int i = t; i < NB; i += 256)
            if (h[i]) atomicAdd(&bcnt[i], h[i]);
    } else {
        const int pb = blockIdx.x - HB;
        const int slot = (pb & 7) * 4 + (t >> 6);
        const int l = t & 63;
        if (pb < 8) pack_w_body(W1, W1hi, W1lo, slot, l);
        else        pack_w_body(W2, W2hi, W2lo, slot, l);
    }
}

// ================================================================ GEMM1 body (A=W1, B=emb fp32, 3-term split)
// 128 rows/block, flat bf16 output HS[row*128 + f].
__device__ __forceinline__ void gemm1_body(
        const float* __restrict__ Xf, const uint* __restrict__ Wphi,
        const uint* __restrict__ Wplo, ushort* __restrict__ HS, int N, int bidx, int tid) {
    const int wv = tid >> 6;
    const int l = tid & 63;
    const int q = l >> 4;
    const int cm = l & 15;
    const long rowbase = (long)bidx * 128 + wv * 32;

    bf16x8 bhi[2][4], blo[2][4];
#pragma unroll
    for (int rt = 0; rt < 2; ++rt) {
        const long row = rowbase + rt * 16 + cm;
        const long rc = row < N ? row : (N - 1);
#pragma unroll
        for (int s = 0; s < 4; ++s) {
            const float* xp = Xf + rc * HID + s * 32 + q * 8;
            const float4 a0 = ((const float4*)xp)[0];
            const float4 a1 = ((const float4*)xp)[1];
            uint4 h, lo4;
            split2(a0.x, a0.y, h.x, lo4.x);
            split2(a0.z, a0.w, h.y, lo4.y);
            split2(a1.x, a1.y, h.z, lo4.z);
            split2(a1.z, a1.w, h.w, lo4.w);
            bhi[rt][s] = as_bf16x8(h);
            blo[rt][s] = as_bf16x8(lo4);
        }
    }

    f32x4 acc[2][8];
#pragma unroll
    for (int rt = 0; rt < 2; ++rt)
#pragma unroll
        for (int t = 0; t < 8; ++t) acc[rt][t] = (f32x4)0.0f;

#pragma unroll
    for (int s = 0; s < 4; ++s) {
#pragma unroll
        for (int t = 0; t < 8; ++t) {
            const int fo = ((s * 8 + t) * 64 + l) * 4;
            const bf16x8 whi = as_bf16x8(*(const uint4*)(Wphi + fo));
            const bf16x8 wlo = as_bf16x8(*(const uint4*)(Wplo + fo));
#pragma unroll
            for (int rt = 0; rt < 2; ++rt) {
                acc[rt][t] = __builtin_amdgcn_mfma_f32_16x16x32_bf16(whi, bhi[rt][s], acc[rt][t], 0, 0, 0);
                acc[rt][t] = __builtin_amdgcn_mfma_f32_16x16x32_bf16(whi, blo[rt][s], acc[rt][t], 0, 0, 0);
                acc[rt][t] = __builtin_amdgcn_mfma_f32_16x16x32_bf16(wlo, bhi[rt][s], acc[rt][t], 0, 0, 0);
            }
        }
    }

#pragma unroll
    for (int rt = 0; rt < 2; ++rt) {
        const long row = rowbase + rt * 16 + cm;
        if (row < N) {
#pragma unroll
            for (int t = 0; t < 8; ++t) {
                uint2 o;
                o.x = pack2(acc[rt][t][0], acc[rt][t][1]);
                o.y = pack2(acc[rt][t][2], acc[rt][t][3]);
                *(uint2*)&HS[row * HID + t * 16 + q * 4] = o;
            }
        }
    }
}

// fat: partition (blocks 0..PB-1, starts immediately) || gemm1 (PB..PB+GB-1)
__global__ __launch_bounds__(256) void gemm1_part_kernel(
        const float* __restrict__ emb, const uint* __restrict__ Wphi,
        const uint* __restrict__ Wplo, ushort* __restrict__ HS, int N,
        const int* __restrict__ src, const int* __restrict__ dst,
        int* __restrict__ gcursor, uint* __restrict__ staged, int E, int PB, int NB) {
    __shared__ int hist[400], lbase[400], loff[400];
    const int t = threadIdx.x;
    if ((int)blockIdx.x >= PB) {
        gemm1_body(emb, Wphi, Wplo, HS, N, blockIdx.x - PB, t);
        return;
    }
    const int e0 = blockIdx.x * PCHUNK;
    for (int i = t; i < NB; i += 256) { hist[i] = 0; loff[i] = 0; }
    __syncthreads();
#pragma unroll
    for (int j = 0; j < PCHUNK / 256; ++j) {
        const int e = e0 + j * 256 + t;
        if (e < E) atomicAdd(&hist[dst[e] >> 8], 1);
    }
    __syncthreads();
    for (int b = t; b < NB; b += 256)
        if (hist[b] > 0) lbase[b] = atomicAdd(&gcursor[b], hist[b]);
    __syncthreads();
#pragma unroll
    for (int j = 0; j < PCHUNK / 256; ++j) {
        const int e = e0 + j * 256 + t;
        if (e < E) {
            const int d = dst[e];
            const int b = d >> 8;
            const int pos = lbase[b] + atomicAdd(&loff[b], 1);
            staged[pos] = (uint)src[e] | ((uint)(d & 255) << 17);
        }
    }
}

// ================================================================ bucket scan (writes rps[N]=E sentinel)
__global__ __launch_bounds__(512) void scan_buckets_kernel(const int* __restrict__ bcnt,
                                                           int* bbase, int* gcursor,
                                                           int* rps, int NB, int E, int N) {
    __shared__ int sh[512];
    const int t = threadIdx.x;
    const int v = (t < NB) ? bcnt[t] : 0;
    sh[t] = v;
    __syncthreads();
    for (int off = 1; off < 512; off <<= 1) {
        int x = (t >= off) ? sh[t - off] : 0;
        __syncthreads();
        sh[t] += x;
        __syncthreads();
    }
    const int excl = sh[t] - v;
    if (t < NB) { bbase[t] = excl; gcursor[t] = excl; }
    if (t == NB - 1) bbase[NB] = excl + v;
    if (t == 0) rps[N] = E;
}

// ================================================================ fill: per-bucket deg/scan/invs/col
__global__ __launch_bounds__(256) void fill_bucket_kernel(
        const uint* __restrict__ staged, const int* __restrict__ bbase,
        int* __restrict__ rps, float* __restrict__ invs, int* __restrict__ col, int N) {
    __shared__ int h[256], cur[256], sh[256];
    const int b = blockIdx.x, t = threadIdx.x;
    const int w0 = bbase[b], w1 = bbase[b + 1];
    const int base0 = b << 8;
    h[t] = 0;
    __syncthreads();
    for (int i = w0 + t; i < w1; i += 256) atomicAdd(&h[staged[i] >> 17], 1);
    __syncthreads();
    const int my = h[t];
    sh[t] = my;
    __syncthreads();
    for (int off = 1; off < 256; off <<= 1) {
        int x = (t >= off) ? sh[t - off] : 0;
        __syncthreads();
        sh[t] += x;
        __syncthreads();
    }
    const int start = w0 + sh[t] - my;
    cur[t] = start;
    const int node = base0 + t;
    if (node < N) {
        rps[node] = start;
        invs[node] = rsqrtf((float)my + 1.0f);
    }
    __syncthreads();
    for (int i = w0 + t; i < w1; i += 256) {
        const uint u = staged[i];
        const int p = atomicAdd(&cur[u >> 17], 1);
        col[p] = (int)(u & 0x1FFFFu);
    }
}

// ================================================================ FUSED: pull1 + relu + GEMM2
// Block = 32 nodes. Phase 1 (pull, R7 geometry): 8 lanes/node, acc[16], batch-4
// gathers; x1' = invs*relu(agg*invs + b1) -> LDS (pitch 68 uints, b128-friendly).
// Phase 2 (MFMA): 4 waves, wave = 16-row x 64-col quadrant of the 32x128 tile,
// H2' = x1' @ W2 (hi+lo 2-term) -> flat bf16 HS2.
__global__ __launch_bounds__(256) void fused_mid_kernel(
        const int* __restrict__ rps, const int* __restrict__ col,
        const uint* __restrict__ HS, const float* __restrict__ invs,
        const float* __restrict__ b1, const uint* __restrict__ Wphi,
        const uint* __restrict__ Wplo, ushort* __restrict__ HS2, int N) {
    __shared__ uint Xl[32 * 68];  // 8704 B
    uint4* Xl4 = (uint4*)Xl;      // row pitch = 17 uint4
    const int t = threadIdx.x;
    const int base = blockIdx.x * 32;

    // ---- phase 1: pull 32 nodes
    {
        const int nl = t >> 3;
        const int node = base + nl;
        const int lane = t & 7;
        uint4 h0 = make_uint4(0, 0, 0, 0), h1 = make_uint4(0, 0, 0, 0);
        if (node < N) {
            const int p = rps[node];
            const int d = rps[node + 1] - p;
            const float sn = invs[node];
            const uint4* H4 = (const uint4*)HS;
            const size_t so = (size_t)node * 16 + lane * 2;

            float acc[16];
            {
                float f[16];
                unpack8(H4[so], f);
                unpack8(H4[so + 1], f + 8);
#pragma unroll
                for (int j = 0; j < 16; ++j) acc[j] = f[j] * sn;
            }
            int i = 0;
            for (; i + 4 <= d; i += 4) {
                const int s0 = col[p + i], s1 = col[p + i + 1];
                const int s2 = col[p + i + 2], s3 = col[p + i + 3];
                const float w0 = invs[s0], w1 = invs[s1], w2 = invs[s2], w3 = invs[s3];
                const uint4 a0 = H4[(size_t)s0 * 16 + lane * 2], a0b = H4[(size_t)s0 * 16 + lane * 2 + 1];
                const uint4 a1 = H4[(size_t)s1 * 16 + lane * 2], a1b = H4[(size_t)s1 * 16 + lane * 2 + 1];
                const uint4 a2 = H4[(size_t)s2 * 16 + lane * 2], a2b = H4[(size_t)s2 * 16 + lane * 2 + 1];
                const uint4 a3 = H4[(size_t)s3 * 16 + lane * 2], a3b = H4[(size_t)s3 * 16 + lane * 2 + 1];
                float f[16];
                unpack8(a0, f); unpack8(a0b, f + 8);
#pragma unroll
                for (int j = 0; j < 16; ++j) acc[j] += f[j] * w0;
                unpack8(a1, f); unpack8(a1b, f + 8);
#pragma unroll
                for (int j = 0; j < 16; ++j) acc[j] += f[j] * w1;
                unpack8(a2, f); unpack8(a2b, f + 8);
#pragma unroll
                for (int j = 0; j < 16; ++j) acc[j] += f[j] * w2;
                unpack8(a3, f); unpack8(a3b, f + 8);
#pragma unroll
                for (int j = 0; j < 16; ++j) acc[j] += f[j] * w3;
            }
            for (; i < d; ++i) {
                const int s0 = col[p + i];
                const float w0 = invs[s0];
                const uint4 a0 = H4[(size_t)s0 * 16 + lane * 2], a0b = H4[(size_t)s0 * 16 + lane * 2 + 1];
                float f[16];
                unpack8(a0, f); unpack8(a0b, f + 8);
#pragma unroll
                for (int j = 0; j < 16; ++j) acc[j] += f[j] * w0;
            }
            float x[16];
#pragma unroll
            for (int j = 0; j < 16; ++j)
                x[j] = sn * fmaxf(acc[j] * sn + b1[lane * 16 + j], 0.0f);  // pre-scaled X1'
            h0.x = pack2(x[0], x[1]);   h0.y = pack2(x[2], x[3]);
            h0.z = pack2(x[4], x[5]);   h0.w = pack2(x[6], x[7]);
            h1.x = pack2(x[8], x[9]);   h1.y = pack2(x[10], x[11]);
            h1.z = pack2(x[12], x[13]); h1.w = pack2(x[14], x[15]);
        }
        Xl4[nl * 17 + lane * 2]     = h0;
        Xl4[nl * 17 + lane * 2 + 1] = h1;
    }
    __syncthreads();

    // ---- phase 2: 32x128 MFMA tile, wave = (row half, col half) quadrant
    {
        const int wv = t >> 6;
        const int l = t & 63;
        const int q = l >> 4;
        const int cm = l & 15;
        const int rH = wv & 1;
        const int cH = wv >> 1;
        const int rl = rH * 16 + cm;  // local row 0..31

        bf16x8 bh[4];
#pragma unroll
        for (int s = 0; s < 4; ++s) bh[s] = as_bf16x8(Xl4[rl * 17 + s * 4 + q]);

        f32x4 acc[4];
#pragma unroll
        for (int tt = 0; tt < 4; ++tt) acc[tt] = (f32x4)0.0f;

#pragma unroll
        for (int s = 0; s < 4; ++s) {
#pragma unroll
            for (int tt = 0; tt < 4; ++tt) {
                const int tg = cH * 4 + tt;
                const int fo = ((s * 8 + tg) * 64 + l) * 4;
                const bf16x8 whi = as_bf16x8(*(const uint4*)(Wphi + fo));
                const bf16x8 wlo = as_bf16x8(*(const uint4*)(Wplo + fo));
                acc[tt] = __builtin_amdgcn_mfma_f32_16x16x32_bf16(whi, bh[s], acc[tt], 0, 0, 0);
                acc[tt] = __builtin_amdgcn_mfma_f32_16x16x32_bf16(wlo, bh[s], acc[tt], 0, 0, 0);
            }
        }

        const long row = (long)base + rl;
        if (row < N) {
#pragma unroll
            for (int tt = 0; tt < 4; ++tt) {
                uint2 o;
                o.x = pack2(acc[tt][0], acc[tt][1]);
                o.y = pack2(acc[tt][2], acc[tt][3]);
                *(uint2*)&HS2[row * HID + cH * 64 + tt * 16 + q * 4] = o;
            }
        }
    }
}

// ================================================================ pull2 + relu + out-GEMM (128->10)
// HS2 = H2' (rows pre-scaled by invs[src]); 8 lanes/node, acc[16], batch-4.
// W_out in LDS float4 slots [c*32 + j4*8 + l] (l=lane 0..7, j4=feature quad).
__global__ __launch_bounds__(256) void pull_out_kernel(
        const int* __restrict__ rps, const int* __restrict__ col,
        const uint* __restrict__ HS2, const float* __restrict__ invs,
        const float* __restrict__ b2, const float* __restrict__ Wout,
        const float* __restrict__ bout, float* __restrict__ OUT, int N) {
    __shared__ float Wd[320 * 4];
    for (int t = threadIdx.x; t < 320; t += 256) {
        const int c = t >> 5, rem = t & 31, j4 = rem >> 3, l = rem & 7;
        const int k0 = l * 16 + j4 * 4;
        float4 w;
        w.x = Wout[(k0 + 0) * NCLASS + c];
        w.y = Wout[(k0 + 1) * NCLASS + c];
        w.z = Wout[(k0 + 2) * NCLASS + c];
        w.w = Wout[(k0 + 3) * NCLASS + c];
        ((float4*)Wd)[t] = w;
    }
    __syncthreads();

    const int g = blockIdx.x * 256 + threadIdx.x;
    const int node = g >> 3;
    if (node >= N) return;
    const int lane = g & 7;
    const int p = rps[node];
    const int d = rps[node + 1] - p;
    const uint4* H4 = (const uint4*)HS2;
    const size_t so = (size_t)node * 16 + lane * 2;

    float acc[16];
    {
        float f[16];
        unpack8(H4[so], f);
        unpack8(H4[so + 1], f + 8);
#pragma unroll
        for (int j = 0; j < 16; ++j) acc[j] = f[j];  // self-loop (already invs-scaled)
    }
    int i = 0;
    for (; i + 4 <= d; i += 4) {
        const int s0 = col[p + i], s1 = col[p + i + 1], s2 = col[p + i + 2], s3 = col[p + i + 3];
        const uint4 a0 = H4[(size_t)s0 * 16 + lane * 2], a0b = H4[(size_t)s0 * 16 + lane * 2 + 1];
        const uint4 a1 = H4[(size_t)s1 * 16 + lane * 2], a1b = H4[(size_t)s1 * 16 + lane * 2 + 1];
        const uint4 a2 = H4[(size_t)s2 * 16 + lane * 2], a2b = H4[(size_t)s2 * 16 + lane * 2 + 1];
        const uint4 a3 = H4[(size_t)s3 * 16 + lane * 2], a3b = H4[(size_t)s3 * 16 + lane * 2 + 1];
        float f[16];
        unpack8(a0, f); unpack8(a0b, f + 8);
#pragma unroll
        for (int j = 0; j < 16; ++j) acc[j] += f[j];
        unpack8(a1, f); unpack8(a1b, f + 8);
#pragma unroll
        for (int j = 0; j < 16; ++j) acc[j] += f[j];
        unpack8(a2, f); unpack8(a2b, f + 8);
#pragma unroll
        for (int j = 0; j < 16; ++j) acc[j] += f[j];
        unpack8(a3, f); unpack8(a3b, f + 8);
#pragma unroll
        for (int j = 0; j < 16; ++j) acc[j] += f[j];
    }
    for (; i < d; ++i) {
        const int s0 = col[p + i];
        const uint4 a0 = H4[(size_t)s0 * 16 + lane * 2], a0b = H4[(size_t)s0 * 16 + lane * 2 + 1];
        float f[16];
        unpack8(a0, f); unpack8(a0b, f + 8);
#pragma unroll
        for (int j = 0; j < 16; ++j) acc[j] += f[j];
    }
    const float sn = invs[node];
    float x[16];
#pragma unroll
    for (int j = 0; j < 16; ++j) x[j] = fmaxf(acc[j] * sn + b2[lane * 16 + j], 0.0f);

    const float4 xv0 = make_float4(x[0], x[1], x[2], x[3]);
    const float4 xv1 = make_float4(x[4], x[5], x[6], x[7]);
    const float4 xv2 = make_float4(x[8], x[9], x[10], x[11]);
    const float4 xv3 = make_float4(x[12], x[13], x[14], x[15]);
    const float4* Wd4 = (const float4*)Wd;
    float resA = 0.0f, resB = 0.0f;
#pragma unroll
    for (int c = 0; c < NCLASS; ++c) {
        const float4* wp = Wd4 + c * 32 + lane;
        const float4 w0 = wp[0], w1 = wp[8], w2 = wp[16], w3 = wp[24];
        float s = xv0.x * w0.x + xv0.y * w0.y + xv0.z * w0.z + xv0.w * w0.w
                + xv1.x * w1.x + xv1.y * w1.y + xv1.z * w1.z + xv1.w * w1.w
                + xv2.x * w2.x + xv2.y * w2.y + xv2.z * w2.z + xv2.w * w2.w
                + xv3.x * w3.x + xv3.y * w3.y + xv3.z * w3.z + xv3.w * w3.w;
        s += __shfl_xor(s, 1, 8);
        s += __shfl_xor(s, 2, 8);
        s += __shfl_xor(s, 4, 8);
        if (c < 8) { if (lane == c) resA = s; }
        else       { if (lane == c - 8) resB = s; }
    }
    OUT[(size_t)node * NCLASS + lane] = resA + bout[lane];
    if (lane < 2) OUT[(size_t)node * NCLASS + 8 + lane] = resB + bout[8 + lane];
}

// ================================================================ launch
extern "C" void kernel_launch(void* const* d_in, const int* in_sizes, int n_in,
                              void* d_out, int out_size, void* d_ws, size_t ws_size,
                              hipStream_t stream) {
    const int* ei     = (const int*)d_in[0];
    const float* emb  = (const float*)d_in[1];
    const float* W1   = (const float*)d_in[2];
    const float* b1   = (const float*)d_in[3];
    const float* W2   = (const float*)d_in[4];
    const float* b2   = (const float*)d_in[5];
    const float* Wout = (const float*)d_in[6];
    const float* bout = (const float*)d_in[7];
    float* out        = (float*)d_out;

    const int E = in_sizes[0] / 2;
    const int N = in_sizes[1] / HID;
    const int* src = ei;
    const int* dst = ei + E;
    (void)ws_size; (void)n_in; (void)out_size;

    const int GB = (N + 127) / 128;            // 782 gemm1 blocks
    const int FB = (N + 31) / 32;              // 3125 fused/pull blocks
    const int NB = (N + 255) >> 8;             // 391 buckets
    const int PB = (E + PCHUNK - 1) / PCHUNK;  // 196 partition blocks

    char* ws = (char*)d_ws;
    size_t off = 0;
    auto alloc = [&](size_t bytes) {
        void* p = ws + off;
        off = (off + bytes + 4095) & ~(size_t)4095;
        return p;
    };
    int*   bcnt    = (int*)alloc(512 * 4);
    int*   bbase   = (int*)alloc(512 * 4);
    int*   gcursor = (int*)alloc(512 * 4);
    int*   rps     = (int*)alloc((size_t)(N + 1) * 4);
    float* invs    = (float*)alloc((size_t)N * 4);
    int*   col     = (int*)alloc((size_t)E * 4);
    uint*  staged  = (uint*)alloc((size_t)E * 4);
    uint*  Wp1hi   = (uint*)alloc(HID * HID * 2);
    uint*  Wp1lo   = (uint*)alloc(HID * HID * 2);
    uint*  Wp2hi   = (uint*)alloc(HID * HID * 2);
    uint*  Wp2lo   = (uint*)alloc(HID * HID * 2);
    uint*  HS      = (uint*)alloc((size_t)N * HID * 2);  // bf16 H1 (flat)
    uint*  HS2     = (uint*)alloc((size_t)N * HID * 2);  // bf16 H2' (flat)

    hipMemsetAsync(bcnt, 0, 512 * 4, stream);
    // bucket histogram || pack W1/W2
    hist_pack_kernel<<<HB + 16, 256, 0, stream>>>(dst, bcnt, E, NB,
                                                  W1, Wp1hi, Wp1lo, W2, Wp2hi, Wp2lo);
    scan_buckets_kernel<<<1, 512, 0, stream>>>(bcnt, bbase, gcursor, rps, NB, E, N);
    // partition (blocks 0..PB-1) || gemm1 emb@W1 -> HS (flat bf16)
    gemm1_part_kernel<<<PB + GB, 256, 0, stream>>>(emb, Wp1hi, Wp1lo, (ushort*)HS, N,
                                                   src, dst, gcursor, staged, E, PB, NB);
    fill_bucket_kernel<<<NB, 256, 0, stream>>>(staged, bbase, rps, invs, col, N);

    // fused: pull1 + relu + GEMM2 -> HS2 (H2', rows pre-scaled by invs)
    fused_mid_kernel<<<FB, 256, 0, stream>>>(rps, col, HS, invs, b1,
                                             Wp2hi, Wp2lo, (ushort*)HS2, N);

    // pull2 + relu + out-GEMM
    pull_out_kernel<<<FB, 256, 0, stream>>>(rps, col, HS2, invs, b2, Wout, bout, out, N);
}